// Round 4
// baseline (235.761 us; speedup 1.0000x reference)
//
#include <hip/hip_runtime.h>
#include <hip/hip_bf16.h>

typedef __bf16 bf16x8 __attribute__((ext_vector_type(8)));
typedef float  f32x4  __attribute__((ext_vector_type(4)));

#define B_ROWS 4096
#define NROWS  8192
#define DDIM   512
// exp(sim/T) = exp2(sim * (1/T)/ln2), T=0.5 -> 2/ln2
#define SCALE2 2.8853900817779268f

// ---------------- normalize: fp32 rows -> bf16 normalized rows in ws ----------------
// Also zero-inits rowsum[] and out[] (replaces memset nodes).
__global__ __launch_bounds__(256) void normalize_kernel(
    const float* __restrict__ h1, const float* __restrict__ h2,
    __bf16* __restrict__ zb, float* __restrict__ rowsum, float* __restrict__ out) {
  int gid = blockIdx.x * 256 + threadIdx.x;
  if (gid < NROWS) rowsum[gid] = 0.0f;
  if (gid == 0) out[0] = 0.0f;

  int wave = threadIdx.x >> 6;
  int lane = threadIdx.x & 63;
  int row  = blockIdx.x * 4 + wave;
  const float* src = (row < B_ROWS) ? (h1 + (size_t)row * DDIM)
                                    : (h2 + (size_t)(row - B_ROWS) * DDIM);
  float4 v0 = *(const float4*)(src + lane * 8);
  float4 v1 = *(const float4*)(src + lane * 8 + 4);
  float ss = v0.x*v0.x + v0.y*v0.y + v0.z*v0.z + v0.w*v0.w
           + v1.x*v1.x + v1.y*v1.y + v1.z*v1.z + v1.w*v1.w;
  #pragma unroll
  for (int m = 1; m <= 32; m <<= 1) ss += __shfl_xor(ss, m);
  float scale = 1.0f / fmaxf(sqrtf(ss), 1e-8f);
  bf16x8 o;
  o[0] = (__bf16)(v0.x*scale); o[1] = (__bf16)(v0.y*scale);
  o[2] = (__bf16)(v0.z*scale); o[3] = (__bf16)(v0.w*scale);
  o[4] = (__bf16)(v1.x*scale); o[5] = (__bf16)(v1.y*scale);
  o[6] = (__bf16)(v1.z*scale); o[7] = (__bf16)(v1.w*scale);
  *(bf16x8*)(zb + (size_t)row * DDIM + lane * 8) = o;
}

// ---------------- fused sim GEMM + exp + row-sum, lower-triangle blocks only --------
// NO LDS, NO BARRIERS: zb is 8 MiB (L2/L3-resident), so each wave loads MFMA
// fragments directly from global. Removes the barrier-synchronized latency drain
// that capped the LDS version at MfmaUtil ~17% (R2/R3 both 84 us); the compiler is
// free to software-pipeline fragment loads across K-iterations via vmcnt.
// grid.x = 2080 triangular 128x128 blocks; off-diagonal blocks emit row-sums AND
// col-sums (symmetry). Blocks with bi-bj == 32 also harvest pos[] (the +B diagonal).
__global__ __launch_bounds__(256) void simexp_kernel(
    const __bf16* __restrict__ zb, float* __restrict__ rowsum,
    float* __restrict__ pos) {
  const int tid  = threadIdx.x;
  const int wave = tid >> 6;
  const int lane = tid & 63;
  const int wm = wave >> 1, wn = wave & 1;
  const int quad = lane >> 4;
  const int l16  = lane & 15;

  // unrank triangular block index: t = bi*(bi+1)/2 + bj, bi >= bj
  int t  = blockIdx.x;
  int bi = (int)((sqrtf(8.0f * (float)t + 1.0f) - 1.0f) * 0.5f);
  while ((bi + 1) * (bi + 2) / 2 <= t) ++bi;
  while (bi * (bi + 1) / 2 > t) --bi;
  int bj = t - bi * (bi + 1) / 2;
  const int rowBlk = bi * 128;
  const int colBlk = bj * 128;
  const bool isDiag = (bi == bj);

  // A-operand layout for mfma_f32_16x16x32_bf16: lane holds A[m=lane&15][k=quad*8+j]
  // -> each fragment load is 16 rows x 16 contiguous bytes (64B/row with the quads).
  const __bf16* aBase = zb + (size_t)(rowBlk + wm * 64 + l16) * DDIM + quad * 8;
  const __bf16* bBase = zb + (size_t)(colBlk + wn * 64 + l16) * DDIM + quad * 8;

  f32x4 acc[4][4] = {};

  #pragma unroll 4
  for (int kt = 0; kt < 16; ++kt) {
    const int k0 = kt * 32;
    bf16x8 afr[4], bfr[4];
    #pragma unroll
    for (int rt = 0; rt < 4; ++rt)
      afr[rt] = *(const bf16x8*)(aBase + rt * 16 * DDIM + k0);
    #pragma unroll
    for (int ct = 0; ct < 4; ++ct)
      bfr[ct] = *(const bf16x8*)(bBase + ct * 16 * DDIM + k0);
    #pragma unroll
    for (int rt = 0; rt < 4; ++rt)
      #pragma unroll
      for (int ct = 0; ct < 4; ++ct)
        acc[rt][ct] = __builtin_amdgcn_mfma_f32_16x16x32_bf16(
            afr[rt], bfr[ct], acc[rt][ct], 0, 0, 0);
  }

  // epilogue: e = exp2(sim*SCALE2); C/D layout: col = lane&15, row = quad*4 + reg
  const bool posBlk = (bi - bj == 32);  // contains the +B diagonal
  float colpart[4] = {0.f, 0.f, 0.f, 0.f};
  #pragma unroll
  for (int rt = 0; rt < 4; ++rt) {
    #pragma unroll
    for (int r = 0; r < 4; ++r) {
      const int grow = rowBlk + wm * 64 + rt * 16 + quad * 4 + r;
      float s = 0.f;
      #pragma unroll
      for (int ct = 0; ct < 4; ++ct) {
        const int gcol = colBlk + wn * 64 + ct * 16 + l16;
        float sv = acc[rt][ct][r];
        float e = exp2f(sv * SCALE2);
        if (isDiag && grow == gcol) e = 0.f;
        if (posBlk && grow - B_ROWS == gcol) pos[gcol] = sv;
        s += e;
        colpart[ct] += e;
      }
      s += __shfl_xor(s, 1);
      s += __shfl_xor(s, 2);
      s += __shfl_xor(s, 4);
      s += __shfl_xor(s, 8);
      if (l16 == 0) atomicAdd(&rowsum[grow], s);
    }
  }
  if (!isDiag) {
    #pragma unroll
    for (int ct = 0; ct < 4; ++ct) {
      float c = colpart[ct];
      c += __shfl_xor(c, 16);
      c += __shfl_xor(c, 32);
      if (quad == 0)
        atomicAdd(&rowsum[colBlk + wn * 64 + ct * 16 + l16], c);
    }
  }
}

// ---------------- finalize: loss_i = ln(rowsum_i) - 2*pos_{i mod B} ; mean --------
// 32 blocks x 256 threads = one thread per row; tiny (reads 48 KB total).
__global__ __launch_bounds__(256) void finalize_kernel(
    const float* __restrict__ rowsum, const float* __restrict__ pos,
    float* __restrict__ out) {
  __shared__ float red[4];
  const int gid = blockIdx.x * 256 + threadIdx.x;
  float loss = __logf(rowsum[gid]) - 2.0f * pos[gid & (B_ROWS - 1)];
  #pragma unroll
  for (int m = 1; m <= 32; m <<= 1) loss += __shfl_xor(loss, m);
  const int wave = threadIdx.x >> 6;
  const int lane = threadIdx.x & 63;
  if (lane == 0) red[wave] = loss;
  __syncthreads();
  if (threadIdx.x == 0)
    atomicAdd(out, (red[0] + red[1] + red[2] + red[3]) * (1.0f / NROWS));
}

extern "C" void kernel_launch(void* const* d_in, const int* in_sizes, int n_in,
                              void* d_out, int out_size, void* d_ws, size_t ws_size,
                              hipStream_t stream) {
  const float* h1 = (const float*)d_in[0];
  const float* h2 = (const float*)d_in[1];
  float* out = (float*)d_out;
  __bf16* zb = (__bf16*)d_ws;                                        // 8 MiB
  float* rowsum = (float*)((char*)d_ws + (size_t)NROWS * DDIM * 2);  // 32 KiB
  float* pos    = rowsum + NROWS;                                    // 16 KiB

  normalize_kernel<<<NROWS / 4, 256, 0, stream>>>(h1, h2, zb, rowsum, out);
  simexp_kernel<<<64 * 65 / 2, 256, 0, stream>>>(zb, rowsum, pos);
  finalize_kernel<<<NROWS / 256, 256, 0, stream>>>(rowsum, pos, out);
}

// Round 5
// 180.689 us; speedup vs baseline: 1.3048x; 1.3048x over previous
//
#include <hip/hip_runtime.h>
#include <hip/hip_bf16.h>

typedef __bf16 bf16x8 __attribute__((ext_vector_type(8)));
typedef float  f32x4  __attribute__((ext_vector_type(4)));

#define B_ROWS 4096
#define NROWS  8192
#define DDIM   512
// exp(sim/T) = exp2(sim * (1/T)/ln2), T=0.5 -> 2/ln2
#define SCALE2 2.8853900817779268f

// zb tiled layout (MFMA-native): row group R = row>>4, r = row&15, chunk Q = k>>3.
// elem offset = ((R*64 + Q)*16 + r)*8.  An A/B fragment load (16 rows x 8 k-elems,
// lane = quad*16+l16) is then offsets lane*16B within one contiguous 1 KB segment.

// ---------------- normalize: fp32 rows -> bf16 normalized rows, tiled layout -------
__global__ __launch_bounds__(256) void normalize_kernel(
    const float* __restrict__ h1, const float* __restrict__ h2,
    __bf16* __restrict__ zb, float* __restrict__ rowsum, float* __restrict__ out) {
  int gid = blockIdx.x * 256 + threadIdx.x;
  if (gid < NROWS) rowsum[gid] = 0.0f;
  if (gid == 0) out[0] = 0.0f;

  int wave = threadIdx.x >> 6;
  int lane = threadIdx.x & 63;   // lane == chunk index Q within the row
  int row  = blockIdx.x * 4 + wave;
  const float* src = (row < B_ROWS) ? (h1 + (size_t)row * DDIM)
                                    : (h2 + (size_t)(row - B_ROWS) * DDIM);
  float4 v0 = *(const float4*)(src + lane * 8);
  float4 v1 = *(const float4*)(src + lane * 8 + 4);
  float ss = v0.x*v0.x + v0.y*v0.y + v0.z*v0.z + v0.w*v0.w
           + v1.x*v1.x + v1.y*v1.y + v1.z*v1.z + v1.w*v1.w;
  #pragma unroll
  for (int m = 1; m <= 32; m <<= 1) ss += __shfl_xor(ss, m);
  float scale = 1.0f / fmaxf(sqrtf(ss), 1e-8f);
  bf16x8 o;
  o[0] = (__bf16)(v0.x*scale); o[1] = (__bf16)(v0.y*scale);
  o[2] = (__bf16)(v0.z*scale); o[3] = (__bf16)(v0.w*scale);
  o[4] = (__bf16)(v1.x*scale); o[5] = (__bf16)(v1.y*scale);
  o[6] = (__bf16)(v1.z*scale); o[7] = (__bf16)(v1.w*scale);
  const int R = row >> 4, r = row & 15;
  *(bf16x8*)(zb + ((size_t)(R * 64 + lane) * 16 + r) * 8) = o;
}

// ---------------- fused sim GEMM + exp + row-sum, lower-triangle blocks only --------
// NO LDS, NO BARRIERS. Tiled zb makes every fragment load one coalesced 1 KB
// global_load_dwordx4 (fixes R4's 16-line scatter). Register ping-pong prefetch:
// loads for tile kt+1 issue before the MFMAs on tile kt, so vmcnt waits are covered
// by ~16 MFMAs plus cross-wave overlap. grid.x = 2080 triangular 128x128 blocks;
// off-diagonal blocks emit row-sums AND col-sums (symmetry); bi-bj==32 blocks
// harvest pos[] (the +B diagonal).
__global__ __launch_bounds__(256) void simexp_kernel(
    const __bf16* __restrict__ zb, float* __restrict__ rowsum,
    float* __restrict__ pos) {
  const int tid  = threadIdx.x;
  const int wave = tid >> 6;
  const int lane = tid & 63;
  const int wm = wave >> 1, wn = wave & 1;
  const int quad = lane >> 4;
  const int l16  = lane & 15;

  // unrank triangular block index: t = bi*(bi+1)/2 + bj, bi >= bj
  int t  = blockIdx.x;
  int bi = (int)((sqrtf(8.0f * (float)t + 1.0f) - 1.0f) * 0.5f);
  while ((bi + 1) * (bi + 2) / 2 <= t) ++bi;
  while (bi * (bi + 1) / 2 > t) --bi;
  int bj = t - bi * (bi + 1) / 2;
  const int rowBlk = bi * 128;
  const int colBlk = bj * 128;
  const bool isDiag = (bi == bj);

  // fragment stream pointers: row group Rg, per-lane offset lane*16B within segment
  const int laneoff = (quad * 16 + l16) * 8;  // == lane*8 elems == lane*16 B
  const __bf16* aPtr[4];
  const __bf16* bPtr[4];
  #pragma unroll
  for (int rt = 0; rt < 4; ++rt) {
    aPtr[rt] = zb + (size_t)((bi * 8 + wm * 4 + rt) * 64) * 128 + laneoff;
    bPtr[rt] = zb + (size_t)((bj * 8 + wn * 4 + rt) * 64) * 128 + laneoff;
  }
  // K-tile kt advances the chunk index by 4 -> +512 elems (1 KB)

  f32x4 acc[4][4] = {};
  bf16x8 a0[4], b0[4], a1[4], b1[4];

  #pragma unroll
  for (int i = 0; i < 4; ++i) {
    a0[i] = *(const bf16x8*)(aPtr[i]);
    b0[i] = *(const bf16x8*)(bPtr[i]);
  }

  #pragma unroll
  for (int kt = 0; kt < 16; kt += 2) {
    #pragma unroll
    for (int i = 0; i < 4; ++i) {
      a1[i] = *(const bf16x8*)(aPtr[i] + (kt + 1) * 512);
      b1[i] = *(const bf16x8*)(bPtr[i] + (kt + 1) * 512);
    }
    #pragma unroll
    for (int rt = 0; rt < 4; ++rt)
      #pragma unroll
      for (int ct = 0; ct < 4; ++ct)
        acc[rt][ct] = __builtin_amdgcn_mfma_f32_16x16x32_bf16(
            a0[rt], b0[ct], acc[rt][ct], 0, 0, 0);
    if (kt + 2 < 16) {
      #pragma unroll
      for (int i = 0; i < 4; ++i) {
        a0[i] = *(const bf16x8*)(aPtr[i] + (kt + 2) * 512);
        b0[i] = *(const bf16x8*)(bPtr[i] + (kt + 2) * 512);
      }
    }
    #pragma unroll
    for (int rt = 0; rt < 4; ++rt)
      #pragma unroll
      for (int ct = 0; ct < 4; ++ct)
        acc[rt][ct] = __builtin_amdgcn_mfma_f32_16x16x32_bf16(
            a1[rt], b1[ct], acc[rt][ct], 0, 0, 0);
  }

  // epilogue: e = exp2(sim*SCALE2); C/D layout: col = lane&15, row = quad*4 + reg
  const bool posBlk = (bi - bj == 32);  // contains the +B diagonal
  float colpart[4] = {0.f, 0.f, 0.f, 0.f};
  #pragma unroll
  for (int rt = 0; rt < 4; ++rt) {
    #pragma unroll
    for (int r = 0; r < 4; ++r) {
      const int grow = rowBlk + wm * 64 + rt * 16 + quad * 4 + r;
      float s = 0.f;
      #pragma unroll
      for (int ct = 0; ct < 4; ++ct) {
        const int gcol = colBlk + wn * 64 + ct * 16 + l16;
        float sv = acc[rt][ct][r];
        float e = exp2f(sv * SCALE2);
        if (isDiag && grow == gcol) e = 0.f;
        if (posBlk && grow - B_ROWS == gcol) pos[gcol] = sv;
        s += e;
        colpart[ct] += e;
      }
      s += __shfl_xor(s, 1);
      s += __shfl_xor(s, 2);
      s += __shfl_xor(s, 4);
      s += __shfl_xor(s, 8);
      if (l16 == 0) atomicAdd(&rowsum[grow], s);
    }
  }
  if (!isDiag) {
    #pragma unroll
    for (int ct = 0; ct < 4; ++ct) {
      float c = colpart[ct];
      c += __shfl_xor(c, 16);
      c += __shfl_xor(c, 32);
      if (quad == 0)
        atomicAdd(&rowsum[colBlk + wn * 64 + ct * 16 + l16], c);
    }
  }
}

// ---------------- finalize: loss_i = ln(rowsum_i) - 2*pos_{i mod B} ; mean --------
__global__ __launch_bounds__(256) void finalize_kernel(
    const float* __restrict__ rowsum, const float* __restrict__ pos,
    float* __restrict__ out) {
  __shared__ float red[4];
  const int gid = blockIdx.x * 256 + threadIdx.x;
  float loss = __logf(rowsum[gid]) - 2.0f * pos[gid & (B_ROWS - 1)];
  #pragma unroll
  for (int m = 1; m <= 32; m <<= 1) loss += __shfl_xor(loss, m);
  const int wave = threadIdx.x >> 6;
  const int lane = threadIdx.x & 63;
  if (lane == 0) red[wave] = loss;
  __syncthreads();
  if (threadIdx.x == 0)
    atomicAdd(out, (red[0] + red[1] + red[2] + red[3]) * (1.0f / NROWS));
}

extern "C" void kernel_launch(void* const* d_in, const int* in_sizes, int n_in,
                              void* d_out, int out_size, void* d_ws, size_t ws_size,
                              hipStream_t stream) {
  const float* h1 = (const float*)d_in[0];
  const float* h2 = (const float*)d_in[1];
  float* out = (float*)d_out;
  __bf16* zb = (__bf16*)d_ws;                                        // 8 MiB
  float* rowsum = (float*)((char*)d_ws + (size_t)NROWS * DDIM * 2);  // 32 KiB
  float* pos    = rowsum + NROWS;                                    // 16 KiB

  normalize_kernel<<<NROWS / 4, 256, 0, stream>>>(h1, h2, zb, rowsum, out);
  simexp_kernel<<<64 * 65 / 2, 256, 0, stream>>>(zb, rowsum, pos);
  finalize_kernel<<<NROWS / 256, 256, 0, stream>>>(rowsum, pos, out);
}

// Round 6
// 127.413 us; speedup vs baseline: 1.8504x; 1.4181x over previous
//
#include <hip/hip_runtime.h>
#include <hip/hip_bf16.h>

typedef float f32x4 __attribute__((ext_vector_type(4)));
typedef long  lx2   __attribute__((ext_vector_type(2)));

#define B_ROWS 4096
#define NROWS  8192
#define DDIM   512
// exp(sim/T) = exp2(sim * (1/T)/ln2), T=0.5 -> 2/ln2
#define SCALE2 2.8853900817779268f

// zq tiled fp8 layout: segment = (row-group R = row>>4) x (k-group G = k>>6), 1 KB.
// seg base = (R*8+G)*1024. Within: lane l = quad*16+l16 owns 16 B at l*16:
//   bytes 0..7  = A-frag for k-tile 2G   (k = G*64 +      quad*8 + j)
//   bytes 8..15 = A-frag for k-tile 2G+1 (k = G*64 + 32 + quad*8 + j)
// -> one global_load_dwordx4 per fragment-pair, perfectly coalesced (1 KB segment).

// ---------------- normalize: fp32 rows -> fp8 e4m3 normalized rows, tiled ----------
__global__ __launch_bounds__(256) void normalize_kernel(
    const float* __restrict__ h1, const float* __restrict__ h2,
    unsigned char* __restrict__ zq, float* __restrict__ rowsum,
    float* __restrict__ out) {
  int gid = blockIdx.x * 256 + threadIdx.x;
  if (gid < NROWS) rowsum[gid] = 0.0f;
  if (gid == 0) out[0] = 0.0f;

  int wave = threadIdx.x >> 6;
  int lane = threadIdx.x & 63;   // lane handles k = lane*8 .. lane*8+7
  int row  = blockIdx.x * 4 + wave;
  const float* src = (row < B_ROWS) ? (h1 + (size_t)row * DDIM)
                                    : (h2 + (size_t)(row - B_ROWS) * DDIM);
  float4 v0 = *(const float4*)(src + lane * 8);
  float4 v1 = *(const float4*)(src + lane * 8 + 4);
  float ss = v0.x*v0.x + v0.y*v0.y + v0.z*v0.z + v0.w*v0.w
           + v1.x*v1.x + v1.y*v1.y + v1.z*v1.z + v1.w*v1.w;
  #pragma unroll
  for (int m = 1; m <= 32; m <<= 1) ss += __shfl_xor(ss, m);
  float sc = 1.0f / fmaxf(sqrtf(ss), 1e-8f);

  int lo = 0, hi = 0;
  lo = __builtin_amdgcn_cvt_pk_fp8_f32(v0.x*sc, v0.y*sc, lo, 0);
  lo = __builtin_amdgcn_cvt_pk_fp8_f32(v0.z*sc, v0.w*sc, lo, 1);
  hi = __builtin_amdgcn_cvt_pk_fp8_f32(v1.x*sc, v1.y*sc, hi, 0);
  hi = __builtin_amdgcn_cvt_pk_fp8_f32(v1.z*sc, v1.w*sc, hi, 1);
  int2 o = make_int2(lo, hi);

  const int R = row >> 4, r = row & 15;
  const int G = lane >> 3, g8 = lane & 7;
  const int quad = g8 & 3, half = g8 >> 2;
  *(int2*)(zq + (size_t)(R * 8 + G) * 1024 + (quad * 16 + r) * 16 + half * 8) = o;
}

// ---------------- fused sim GEMM (fp8) + exp + row-sum, lower-triangle blocks ------
// NO LDS, NO BARRIERS. Per super-iter (K=64): 8 coalesced dwordx4 loads -> 32 MFMA
// (fp8 non-scaled = bf16 rate, half the bytes of R5). Register ping-pong prefetch.
// grid.x = 2080 triangular 128x128 blocks; off-diagonal blocks emit row-sums AND
// col-sums (symmetry); bi-bj==32 blocks harvest pos[] (the +B diagonal).
__global__ __launch_bounds__(256) void simexp_kernel(
    const unsigned char* __restrict__ zq, float* __restrict__ rowsum,
    float* __restrict__ pos) {
  const int tid  = threadIdx.x;
  const int wave = tid >> 6;
  const int lane = tid & 63;
  const int wm = wave >> 1, wn = wave & 1;
  const int quad = lane >> 4;
  const int l16  = lane & 15;

  // unrank triangular block index: t = bi*(bi+1)/2 + bj, bi >= bj
  int t  = blockIdx.x;
  int bi = (int)((sqrtf(8.0f * (float)t + 1.0f) - 1.0f) * 0.5f);
  while ((bi + 1) * (bi + 2) / 2 <= t) ++bi;
  while (bi * (bi + 1) / 2 > t) --bi;
  int bj = t - bi * (bi + 1) / 2;
  const int rowBlk = bi * 128;
  const int colBlk = bj * 128;
  const bool isDiag = (bi == bj);

  const unsigned char* aPtr[4];
  const unsigned char* bPtr[4];
  #pragma unroll
  for (int rt = 0; rt < 4; ++rt) {
    aPtr[rt] = zq + (size_t)(bi * 8 + wm * 4 + rt) * 8192 + lane * 16;
    bPtr[rt] = zq + (size_t)(bj * 8 + wn * 4 + rt) * 8192 + lane * 16;
  }
  // k-group G advances +1024 B per super-iter (K=64), 8 super-iters total.

  f32x4 acc[4][4] = {};
  lx2 a0[4], b0[4], a1[4], b1[4];

  #pragma unroll
  for (int i = 0; i < 4; ++i) {
    a0[i] = *(const lx2*)(aPtr[i]);
    b0[i] = *(const lx2*)(bPtr[i]);
  }

  #pragma unroll
  for (int G = 0; G < 8; G += 2) {
    #pragma unroll
    for (int i = 0; i < 4; ++i) {
      a1[i] = *(const lx2*)(aPtr[i] + (G + 1) * 1024);
      b1[i] = *(const lx2*)(bPtr[i] + (G + 1) * 1024);
    }
    #pragma unroll
    for (int rt = 0; rt < 4; ++rt)
      #pragma unroll
      for (int ct = 0; ct < 4; ++ct) {
        acc[rt][ct] = __builtin_amdgcn_mfma_f32_16x16x32_fp8_fp8(
            a0[rt].x, b0[ct].x, acc[rt][ct], 0, 0, 0);
        acc[rt][ct] = __builtin_amdgcn_mfma_f32_16x16x32_fp8_fp8(
            a0[rt].y, b0[ct].y, acc[rt][ct], 0, 0, 0);
      }
    if (G + 2 < 8) {
      #pragma unroll
      for (int i = 0; i < 4; ++i) {
        a0[i] = *(const lx2*)(aPtr[i] + (G + 2) * 1024);
        b0[i] = *(const lx2*)(bPtr[i] + (G + 2) * 1024);
      }
    }
    #pragma unroll
    for (int rt = 0; rt < 4; ++rt)
      #pragma unroll
      for (int ct = 0; ct < 4; ++ct) {
        acc[rt][ct] = __builtin_amdgcn_mfma_f32_16x16x32_fp8_fp8(
            a1[rt].x, b1[ct].x, acc[rt][ct], 0, 0, 0);
        acc[rt][ct] = __builtin_amdgcn_mfma_f32_16x16x32_fp8_fp8(
            a1[rt].y, b1[ct].y, acc[rt][ct], 0, 0, 0);
      }
  }

  // epilogue: e = exp2(sim*SCALE2); C/D layout: col = lane&15, row = quad*4 + reg
  // (C/D layout is dtype-independent on gfx950 — m121-m128)
  const bool posBlk = (bi - bj == 32);  // contains the +B diagonal
  float colpart[4] = {0.f, 0.f, 0.f, 0.f};
  #pragma unroll
  for (int rt = 0; rt < 4; ++rt) {
    #pragma unroll
    for (int r = 0; r < 4; ++r) {
      const int grow = rowBlk + wm * 64 + rt * 16 + quad * 4 + r;
      float s = 0.f;
      #pragma unroll
      for (int ct = 0; ct < 4; ++ct) {
        const int gcol = colBlk + wn * 64 + ct * 16 + l16;
        float sv = acc[rt][ct][r];
        float e = exp2f(sv * SCALE2);
        if (isDiag && grow == gcol) e = 0.f;
        if (posBlk && grow - B_ROWS == gcol) pos[gcol] = sv;
        s += e;
        colpart[ct] += e;
      }
      s += __shfl_xor(s, 1);
      s += __shfl_xor(s, 2);
      s += __shfl_xor(s, 4);
      s += __shfl_xor(s, 8);
      if (l16 == 0) atomicAdd(&rowsum[grow], s);
    }
  }
  if (!isDiag) {
    #pragma unroll
    for (int ct = 0; ct < 4; ++ct) {
      float c = colpart[ct];
      c += __shfl_xor(c, 16);
      c += __shfl_xor(c, 32);
      if (quad == 0)
        atomicAdd(&rowsum[colBlk + wn * 64 + ct * 16 + l16], c);
    }
  }
}

// ---------------- finalize: loss_i = ln(rowsum_i) - 2*pos_{i mod B} ; mean --------
__global__ __launch_bounds__(256) void finalize_kernel(
    const float* __restrict__ rowsum, const float* __restrict__ pos,
    float* __restrict__ out) {
  __shared__ float red[4];
  const int gid = blockIdx.x * 256 + threadIdx.x;
  float loss = __logf(rowsum[gid]) - 2.0f * pos[gid & (B_ROWS - 1)];
  #pragma unroll
  for (int m = 1; m <= 32; m <<= 1) loss += __shfl_xor(loss, m);
  const int wave = threadIdx.x >> 6;
  const int lane = threadIdx.x & 63;
  if (lane == 0) red[wave] = loss;
  __syncthreads();
  if (threadIdx.x == 0)
    atomicAdd(out, (red[0] + red[1] + red[2] + red[3]) * (1.0f / NROWS));
}

extern "C" void kernel_launch(void* const* d_in, const int* in_sizes, int n_in,
                              void* d_out, int out_size, void* d_ws, size_t ws_size,
                              hipStream_t stream) {
  const float* h1 = (const float*)d_in[0];
  const float* h2 = (const float*)d_in[1];
  float* out = (float*)d_out;
  unsigned char* zq = (unsigned char*)d_ws;                       // 4 MiB fp8
  float* rowsum = (float*)((char*)d_ws + (size_t)NROWS * DDIM);   // 32 KiB
  float* pos    = rowsum + NROWS;                                 // 16 KiB

  normalize_kernel<<<NROWS / 4, 256, 0, stream>>>(h1, h2, zq, rowsum, out);
  simexp_kernel<<<64 * 65 / 2, 256, 0, stream>>>(zq, rowsum, pos);
  finalize_kernel<<<NROWS / 256, 256, 0, stream>>>(rowsum, pos, out);
}